// Round 1
// baseline (1498.830 us; speedup 1.0000x reference)
//
#include <hip/hip_runtime.h>

constexpr int kN = 100000;
constexpr int kE = 800000;
constexpr int kB = 128;
constexpr float kInvBN = 0.99999500003749968f; // 1/sqrt(1+1e-5)

// ---------------- CSR build ----------------

__global__ __launch_bounds__(256) void count_kernel(const int* __restrict__ ei,
                                                    const int* __restrict__ ed,
                                                    int* __restrict__ cnt) {
  int e = blockIdx.x * 256 + threadIdx.x;
  if (e >= kE) return;
  atomicAdd(&cnt[ed[e] * kN + ei[kE + e]], 1);
}

__global__ __launch_bounds__(256) void scan1_kernel(const int* __restrict__ in,
                                                    int* __restrict__ out,
                                                    int* __restrict__ bsum, int M) {
  __shared__ int s[256];
  int t = threadIdx.x;
  int idx = blockIdx.x * 1024 + t * 4;
  int4 v = {0, 0, 0, 0};
  if (idx < M) v = *(const int4*)&in[idx];
  int tsum = v.x + v.y + v.z + v.w;
  s[t] = tsum;
  __syncthreads();
  for (int d = 1; d < 256; d <<= 1) {
    int tmp = (t >= d) ? s[t - d] : 0;
    __syncthreads();
    s[t] += tmp;
    __syncthreads();
  }
  int excl = s[t] - tsum;
  if (idx < M) {
    int4 o;
    o.x = excl; o.y = excl + v.x; o.z = o.y + v.y; o.w = o.z + v.z;
    *(int4*)&out[idx] = o;
  }
  if (t == 255) bsum[blockIdx.x] = s[255];
}

__global__ __launch_bounds__(256) void scan2_kernel(int* __restrict__ bsum, int nb) {
  __shared__ int s[256];
  int t = threadIdx.x;
  int v = (t < nb) ? bsum[t] : 0;
  s[t] = v;
  __syncthreads();
  for (int d = 1; d < 256; d <<= 1) {
    int tmp = (t >= d) ? s[t - d] : 0;
    __syncthreads();
    s[t] += tmp;
    __syncthreads();
  }
  if (t < nb) bsum[t] = s[t] - v;
}

__global__ __launch_bounds__(256) void scan3_kernel(int* __restrict__ out,
                                                    const int* __restrict__ bsum, int M) {
  int idx = blockIdx.x * 1024 + threadIdx.x * 4;
  int add = bsum[blockIdx.x];
  if (idx < M) {
    int4 o = *(int4*)&out[idx];
    o.x += add; o.y += add; o.z += add; o.w += add;
    *(int4*)&out[idx] = o;
  }
}

__global__ __launch_bounds__(256) void fill_kernel(const int* __restrict__ ei,
                                                   const int* __restrict__ ed,
                                                   const int* __restrict__ off,
                                                   int* __restrict__ cursor,
                                                   int* __restrict__ csr) {
  int e = blockIdx.x * 256 + threadIdx.x;
  if (e >= kE) return;
  int bkt = ed[e] * kN + ei[kE + e];
  int pos = atomicAdd(&cursor[bkt], 1);
  csr[off[bkt] + pos] = ei[e];
}

__global__ __launch_bounds__(256) void inv_kernel(const int* __restrict__ cnt,
                                                  float* __restrict__ inv) {
  int i = blockIdx.x * 256 + threadIdx.x;
  if (i < 2 * kN) inv[i] = 1.0f / fmaxf((float)cnt[i], 1.0f);
}

// ---------------- Aggregation: one wave per node ----------------

__global__ __launch_bounds__(256) void agg_kernel(const float* __restrict__ h,
                                                  float* __restrict__ aggout,
                                                  const int* __restrict__ off,
                                                  const int* __restrict__ cnt,
                                                  const int* __restrict__ csr,
                                                  const float* __restrict__ inv,
                                                  int dirbase) {
  int node = blockIdx.x * 4 + (threadIdx.x >> 6);
  int lane = threadIdx.x & 63;
  int bkt = dirbase + node;
  int s = off[bkt];
  int c = cnt[bkt];
  float2 acc = {0.f, 0.f};
  for (int e2 = 0; e2 < c; ++e2) {
    int src = csr[s + e2];
    float2 v = *(const float2*)&h[src * 128 + lane * 2];
    acc.x += v.x;
    acc.y += v.y;
  }
  float iv = inv[bkt];
  float2 r = {acc.x * iv, acc.y * iv};
  *(float2*)&aggout[node * 128 + lane * 2] = r;
}

// ---------------- Fused layer GEMM: out = relu([mean,h] @ [Wl;Wr]^T + b), in-place in mean ----------------

constexpr int kNPT = 32;  // nodes per tile; 100000 % 32 == 0

__global__ __launch_bounds__(256) void layer_kernel(float* __restrict__ mean_io,
                                                    const float* __restrict__ h,
                                                    const float* __restrict__ Wl,
                                                    const float* __restrict__ Wr,
                                                    const float* __restrict__ bl) {
  __shared__ float wT[256 * 128];   // wT[k][o], k<128 -> Wl, k>=128 -> Wr
  __shared__ float vl[kNPT * 128];  // v[n][k] natural layout
  const int t = threadIdx.x;

  // Stage weights transposed (coalesced global reads; LDS write conflicts amortized over tiles)
  for (int f = t; f < 128 * 128; f += 256) {
    int o = f >> 7, k = f & 127;
    float a = Wl[f];
    float b = Wr[f];
    wT[k * 128 + o] = a;
    wT[(k + 128) * 128 + o] = b;
  }
  __syncthreads();

  const int o0 = (t & 31) * 4;  // output base (0..124)
  const int n0 = (t >> 5) * 4;  // node base within tile (0..28)
  const int ntiles = kN / kNPT; // 3125

  for (int tile = blockIdx.x; tile < ntiles; tile += gridDim.x) {
    const int nodebase = tile * kNPT;
    float acc[4][4];
#pragma unroll
    for (int i = 0; i < 4; i++)
#pragma unroll
      for (int j = 0; j < 4; j++) acc[i][j] = 0.f;

    // half 0: v = mean rows
    for (int f = t * 4; f < kNPT * 128; f += 1024)
      *(float4*)&vl[f] = *(const float4*)&mean_io[nodebase * 128 + f];
    __syncthreads();
#pragma unroll 8
    for (int k = 0; k < 128; k++) {
      float4 wv = *(const float4*)&wT[k * 128 + o0];
#pragma unroll
      for (int i = 0; i < 4; i++) {
        float lv = vl[(n0 + i) * 128 + k];
        acc[i][0] += lv * wv.x;
        acc[i][1] += lv * wv.y;
        acc[i][2] += lv * wv.z;
        acc[i][3] += lv * wv.w;
      }
    }
    __syncthreads();

    // half 1: v = h rows
    for (int f = t * 4; f < kNPT * 128; f += 1024)
      *(float4*)&vl[f] = *(const float4*)&h[nodebase * 128 + f];
    __syncthreads();
#pragma unroll 8
    for (int k = 0; k < 128; k++) {
      float4 wv = *(const float4*)&wT[(k + 128) * 128 + o0];
#pragma unroll
      for (int i = 0; i < 4; i++) {
        float lv = vl[(n0 + i) * 128 + k];
        acc[i][0] += lv * wv.x;
        acc[i][1] += lv * wv.y;
        acc[i][2] += lv * wv.z;
        acc[i][3] += lv * wv.w;
      }
    }
    __syncthreads();

    // epilogue: add bias, relu, write in place
    float4 bv = *(const float4*)&bl[o0];
#pragma unroll
    for (int i = 0; i < 4; i++) {
      float4 r;
      r.x = fmaxf(acc[i][0] + bv.x, 0.f);
      r.y = fmaxf(acc[i][1] + bv.y, 0.f);
      r.z = fmaxf(acc[i][2] + bv.z, 0.f);
      r.w = fmaxf(acc[i][3] + bv.w, 0.f);
      *(float4*)&mean_io[(nodebase + n0 + i) * 128 + o0] = r;
    }
  }
}

// ---------------- Pooling ----------------

__device__ inline int lbound(const int* __restrict__ a, int key) {
  int lo = 0, hi = kN;
  while (lo < hi) {
    int mid = (lo + hi) >> 1;
    if (a[mid] < key) lo = mid + 1; else hi = mid;
  }
  return lo;
}

__global__ __launch_bounds__(128) void pool_kernel(const float* __restrict__ h,
                                                   const int* __restrict__ batch,
                                                   float* __restrict__ comb_raw,
                                                   int base) {
  int gb = blockIdx.x;
  int graph = gb >> 3;
  int chunk = gb & 7;
  int t = threadIdx.x;
  int s = lbound(batch, graph);
  int e = lbound(batch, graph + 1);
  int len = e - s;
  int c0 = s + (int)((long long)len * chunk / 8);
  int c1 = s + (int)((long long)len * (chunk + 1) / 8);
  float acc = 0.f;
  for (int n = c0; n < c1; ++n) acc += h[n * 128 + t];
  atomicAdd(&comb_raw[graph * 256 + base + t], acc);
}

// ---------------- Heads ----------------

__global__ __launch_bounds__(64) void head_kernel(
    const float* __restrict__ comb_raw, const int* __restrict__ batch,
    const float* __restrict__ gf,
    const float* __restrict__ neg, const float* __restrict__ neb,
    const float* __restrict__ fc1W, const float* __restrict__ fc1b,
    const float* __restrict__ bn1g, const float* __restrict__ bn1b,
    const float* __restrict__ fc2W, const float* __restrict__ fc2b,
    const float* __restrict__ fc3aW, const float* __restrict__ fc3ab,
    const float* __restrict__ fc3bW, const float* __restrict__ fc3bb,
    const float* __restrict__ ncg, const float* __restrict__ ncb,
    float* __restrict__ out) {
  const int b = blockIdx.x;
  const int lane = threadIdx.x;
  int s = lbound(batch, b);
  int e = lbound(batch, b + 1);
  float cntf = fmaxf((float)(e - s), 1.0f);

  __shared__ float comb[256];
  __shared__ float x3[261];

  for (int j = lane; j < 256; j += 64)
    comb[j] = neg[j] * ((comb_raw[b * 256 + j] / cntf) * kInvBN) + neb[j];
  __syncthreads();

  float g1 = gf[b * 5 + 1], g2 = gf[b * 5 + 2], g3 = gf[b * 5 + 3], g4 = gf[b * 5 + 4];

  // out1: 16 outs, input [comb(256), g4], relu then bn
  for (int o = 0; o < 16; o++) {
    const float* w = &fc1W[o * 257];
    float p = 0.f;
    for (int j = lane; j < 256; j += 64) p += comb[j] * w[j];
    for (int m = 32; m; m >>= 1) p += __shfl_xor(p, m, 64);
    float z = p + w[256] * g4 + fc1b[o];
    z = fmaxf(z, 0.f);
    float r = bn1g[o] * (z * kInvBN) + bn1b[o];
    if (lane == 0) out[b * 16 + o] = r;
  }

  // out2: 2 outs, input [comb(256), g2,g3,g4]
  float r2[2];
  for (int o = 0; o < 2; o++) {
    const float* w = &fc2W[o * 259];
    float p = 0.f;
    for (int j = lane; j < 256; j += 64) p += comb[j] * w[j];
    for (int m = 32; m; m >>= 1) p += __shfl_xor(p, m, 64);
    float z = p + w[256] * g2 + w[257] * g3 + w[258] * g4 + fc2b[o];
    r2[o] = fmaxf(z, 0.f);
    if (lane == 0) out[2048 + b * 2 + o] = r2[o];
  }
  int pred = (r2[1] > r2[0]) ? 1 : 0;

  // x3 = bn([comb, g2, g1, g2, g3, g4], normc)
  for (int j = lane; j < 261; j += 64) {
    float v;
    if (j < 256) v = comb[j];
    else if (j == 256) v = g2;
    else if (j == 257) v = g1;
    else if (j == 258) v = g2;
    else if (j == 259) v = g3;
    else v = g4;
    x3[j] = ncg[j] * (v * kInvBN) + ncb[j];
  }
  __syncthreads();

  for (int o = 0; o < 4; o++) {
    const float* w = &fc3aW[o * 261];
    float p = 0.f;
    for (int j = lane; j < 261; j += 64) p += x3[j] * w[j];
    for (int m = 32; m; m >>= 1) p += __shfl_xor(p, m, 64);
    float v = p + fc3ab[o];
    if (lane == 0) out[2304 + b * 9 + o] = (pred == 0) ? v : 0.f;
  }
  for (int o = 0; o < 5; o++) {
    const float* w = &fc3bW[o * 261];
    float p = 0.f;
    for (int j = lane; j < 261; j += 64) p += x3[j] * w[j];
    for (int m = 32; m; m >>= 1) p += __shfl_xor(p, m, 64);
    float v = p + fc3bb[o];
    if (lane == 0) out[2304 + b * 9 + 4 + o] = (pred == 1) ? v : 0.f;
  }
}

// ---------------- Launch ----------------

extern "C" void kernel_launch(void* const* d_in, const int* in_sizes, int n_in,
                              void* d_out, int out_size, void* d_ws, size_t ws_size,
                              hipStream_t stream) {
  (void)in_sizes; (void)n_in; (void)out_size; (void)ws_size;
  const float* x   = (const float*)d_in[0];
  const int* ei    = (const int*)d_in[1];
  const int* ed    = (const int*)d_in[2];
  const int* batch = (const int*)d_in[3];
  const float* gf  = (const float*)d_in[4];

  char* ws = (char*)d_ws;
  auto carve = [&](size_t bytes) -> void* {
    void* p = ws;
    ws += (bytes + 255) & ~(size_t)255;
    return p;
  };
  int* cnt        = (int*)carve(2 * kN * sizeof(int));
  int* off        = (int*)carve(2 * kN * sizeof(int));
  int* cursor     = (int*)carve(2 * kN * sizeof(int));
  int* bsum       = (int*)carve(1024);
  int* csr        = (int*)carve(kE * sizeof(int));
  float* inv      = (float*)carve(2 * kN * sizeof(float));
  float* comb_raw = (float*)carve(kB * 256 * sizeof(float));
  float* buf0     = (float*)carve((size_t)kN * 128 * sizeof(float));
  float* buf1     = (float*)carve((size_t)kN * 128 * sizeof(float));

  hipMemsetAsync(cnt, 0, 2 * kN * sizeof(int), stream);
  hipMemsetAsync(cursor, 0, 2 * kN * sizeof(int), stream);
  hipMemsetAsync(comb_raw, 0, kB * 256 * sizeof(float), stream);

  count_kernel<<<(kE + 255) / 256, 256, 0, stream>>>(ei, ed, cnt);
  constexpr int M = 2 * kN;
  constexpr int NB = (M + 1023) / 1024;
  scan1_kernel<<<NB, 256, 0, stream>>>(cnt, off, bsum, M);
  scan2_kernel<<<1, 256, 0, stream>>>(bsum, NB);
  scan3_kernel<<<NB, 256, 0, stream>>>(off, bsum, M);
  fill_kernel<<<(kE + 255) / 256, 256, 0, stream>>>(ei, ed, off, cursor, csr);
  inv_kernel<<<(M + 255) / 256, 256, 0, stream>>>(cnt, inv);

  auto aggL = [&](const float* h, float* a, int dirbase) {
    agg_kernel<<<kN / 4, 256, 0, stream>>>(h, a, off, cnt, csr, inv, dirbase);
  };
  auto layerL = [&](float* a, const float* h, int wi) {
    layer_kernel<<<256, 256, 0, stream>>>(a, h, (const float*)d_in[wi],
                                          (const float*)d_in[wi + 2],
                                          (const float*)d_in[wi + 1]);
  };

  // pre chain (dir bucket base 0)
  aggL(x, buf0, 0);      layerL(buf0, x, 6);
  aggL(buf0, buf1, 0);   layerL(buf1, buf0, 9);
  aggL(buf1, buf0, 0);   layerL(buf0, buf1, 12);
  pool_kernel<<<kB * 8, 128, 0, stream>>>(buf0, batch, comb_raw, 0);

  // suc chain (dir bucket base kN)
  aggL(x, buf1, kN);     layerL(buf1, x, 15);
  aggL(buf1, buf0, kN);  layerL(buf0, buf1, 18);
  aggL(buf0, buf1, kN);  layerL(buf1, buf0, 21);
  pool_kernel<<<kB * 8, 128, 0, stream>>>(buf1, batch, comb_raw, 128);

  head_kernel<<<kB, 64, 0, stream>>>(
      comb_raw, batch, gf,
      (const float*)d_in[24], (const float*)d_in[25],
      (const float*)d_in[26], (const float*)d_in[27],
      (const float*)d_in[28], (const float*)d_in[29],
      (const float*)d_in[30], (const float*)d_in[31],
      (const float*)d_in[32], (const float*)d_in[33],
      (const float*)d_in[34], (const float*)d_in[35],
      (const float*)d_in[36], (const float*)d_in[37],
      (float*)d_out);
}

// Round 2
// 713.708 us; speedup vs baseline: 2.1001x; 2.1001x over previous
//
#include <hip/hip_runtime.h>

constexpr int kN = 100000;
constexpr int kNpad = 100096;      // 782 * 128
constexpr int kE = 800000;
constexpr int kB = 128;
constexpr float kInvBN = 0.99999500003749968f; // 1/sqrt(1+1e-5)

typedef short s16x8 __attribute__((ext_vector_type(8)));
typedef float f32x4 __attribute__((ext_vector_type(4)));

__device__ inline ushort bf16rne(float f) {
  uint u = __builtin_bit_cast(uint, f);
  u += 0x7fffu + ((u >> 16) & 1u);
  return (ushort)(u >> 16);
}
__device__ inline float bflo(uint v) { return __builtin_bit_cast(float, v << 16); }
__device__ inline float bfhi(uint v) { return __builtin_bit_cast(float, v & 0xffff0000u); }

// ---------------- CSR build ----------------

__global__ __launch_bounds__(256) void count_kernel(const int* __restrict__ ei,
                                                    const int* __restrict__ ed,
                                                    int* __restrict__ cnt) {
  int e = blockIdx.x * 256 + threadIdx.x;
  if (e >= kE) return;
  atomicAdd(&cnt[ed[e] * kN + ei[kE + e]], 1);
}

__global__ __launch_bounds__(256) void scan1_kernel(const int* __restrict__ in,
                                                    int* __restrict__ out,
                                                    int* __restrict__ bsum, int M) {
  __shared__ int s[256];
  int t = threadIdx.x;
  int idx = blockIdx.x * 1024 + t * 4;
  int4 v = {0, 0, 0, 0};
  if (idx < M) v = *(const int4*)&in[idx];
  int tsum = v.x + v.y + v.z + v.w;
  s[t] = tsum;
  __syncthreads();
  for (int d = 1; d < 256; d <<= 1) {
    int tmp = (t >= d) ? s[t - d] : 0;
    __syncthreads();
    s[t] += tmp;
    __syncthreads();
  }
  int excl = s[t] - tsum;
  if (idx < M) {
    int4 o;
    o.x = excl; o.y = excl + v.x; o.z = o.y + v.y; o.w = o.z + v.z;
    *(int4*)&out[idx] = o;
  }
  if (t == 255) bsum[blockIdx.x] = s[255];
}

__global__ __launch_bounds__(256) void scan2_kernel(int* __restrict__ bsum, int nb) {
  __shared__ int s[256];
  int t = threadIdx.x;
  int v = (t < nb) ? bsum[t] : 0;
  s[t] = v;
  __syncthreads();
  for (int d = 1; d < 256; d <<= 1) {
    int tmp = (t >= d) ? s[t - d] : 0;
    __syncthreads();
    s[t] += tmp;
    __syncthreads();
  }
  if (t < nb) bsum[t] = s[t] - v;
}

__global__ __launch_bounds__(256) void scan3_kernel(int* __restrict__ out,
                                                    const int* __restrict__ bsum, int M) {
  int idx = blockIdx.x * 1024 + threadIdx.x * 4;
  int add = bsum[blockIdx.x];
  if (idx < M) {
    int4 o = *(int4*)&out[idx];
    o.x += add; o.y += add; o.z += add; o.w += add;
    *(int4*)&out[idx] = o;
  }
}

__global__ __launch_bounds__(256) void fill_kernel(const int* __restrict__ ei,
                                                   const int* __restrict__ ed,
                                                   const int* __restrict__ off,
                                                   int* __restrict__ cursor,
                                                   int* __restrict__ csr) {
  int e = blockIdx.x * 256 + threadIdx.x;
  if (e >= kE) return;
  int bkt = ed[e] * kN + ei[kE + e];
  int pos = atomicAdd(&cursor[bkt], 1);
  csr[off[bkt] + pos] = ei[e];
}

__global__ __launch_bounds__(256) void inv_kernel(const int* __restrict__ cnt,
                                                  float* __restrict__ inv) {
  int i = blockIdx.x * 256 + threadIdx.x;
  if (i < 2 * kN) inv[i] = 1.0f / fmaxf((float)cnt[i], 1.0f);
}

// ---------------- precompute: x -> bf16 (padded), weights -> packed bf16 ----------------

__global__ __launch_bounds__(256) void xconv_kernel(const float* __restrict__ x,
                                                    ushort* __restrict__ xb) {
  int gid = blockIdx.x * 256 + threadIdx.x;
  int i4 = gid * 4;
  if (i4 >= kNpad * 128) return;
  ushort4 r;
  if (i4 < kN * 128) {
    float4 v = *(const float4*)&x[i4];
    r.x = bf16rne(v.x); r.y = bf16rne(v.y); r.z = bf16rne(v.z); r.w = bf16rne(v.w);
  } else {
    r.x = r.y = r.z = r.w = 0;
  }
  *(ushort4*)&xb[i4] = r;
}

// Wb[o][k] bf16, k<128 -> Wl[o][k], k>=128 -> Wr[o][k-128]
__global__ __launch_bounds__(256) void wprep_kernel(const float* __restrict__ Wl,
                                                    const float* __restrict__ Wr,
                                                    ushort* __restrict__ Wb) {
  int id = blockIdx.x * 256 + threadIdx.x; // 0..32767
  int o = id >> 8, k = id & 255;
  float v = (k < 128) ? Wl[o * 128 + k] : Wr[o * 128 + (k - 128)];
  Wb[id] = bf16rne(v);
}

// ---------------- Aggregation (bf16 gather, f32 accum, bf16 out) ----------------

__global__ __launch_bounds__(256) void agg_kernel(const ushort* __restrict__ h,
                                                  ushort* __restrict__ aggout,
                                                  const int* __restrict__ off,
                                                  const int* __restrict__ cnt,
                                                  const int* __restrict__ csr,
                                                  const float* __restrict__ inv,
                                                  int dirbase) {
  int node = blockIdx.x * 4 + (threadIdx.x >> 6);
  int lane = threadIdx.x & 63;
  int bkt = dirbase + node;
  int s = off[bkt];
  int c = cnt[bkt];
  float ax = 0.f, ay = 0.f;
  for (int e2 = 0; e2 < c; ++e2) {
    int src = csr[s + e2];
    uint v = *(const uint*)(h + (size_t)src * 128 + lane * 2);
    ax += bflo(v);
    ay += bfhi(v);
  }
  float iv = inv[bkt];
  uint r = (uint)bf16rne(ax * iv) | ((uint)bf16rne(ay * iv) << 16);
  *(uint*)(aggout + (size_t)node * 128 + lane * 2) = r;
}

// ---------------- MFMA layer: out = relu([mean|h] @ W^T + b), bf16 in/out ----------------
// Operand-swapped: D = mfma(Wfrag, NodeFrag) gives D[o][node]; lane holds 4
// consecutive output channels for one node -> packed 8B stores.

__global__ __launch_bounds__(256) void layer_mfma_kernel(
    ushort* __restrict__ mean_io,     // [kNpad][128] bf16 (also output, in place)
    const ushort* __restrict__ h,     // [kNpad][128] bf16
    const ushort* __restrict__ Wb,    // [128][256] bf16
    const float* __restrict__ bl) {
  __shared__ ushort Wlds[128 * 256];  // 64 KB, 16B-block XOR swizzled

  const int t = threadIdx.x;
  // stage W: chunk u (16B) -> row o = u>>5, block b = u&31, slot b ^ (o&7)
#pragma unroll
  for (int it = 0; it < 16; ++it) {
    int u = t + 256 * it;
    int o = u >> 5, b = u & 31;
    uint4 v = *(const uint4*)(Wb + (size_t)u * 8);
    *(uint4*)((char*)Wlds + o * 512 + ((b ^ (o & 7)) << 4)) = v;
  }
  __syncthreads();

  const int w = t >> 6;
  const int l = t & 63;
  const int lr = l & 15;
  const int lq = l >> 4;
  const int nodebase = blockIdx.x * 128 + w * 32;
  const int swz = lr & 7;   // o&7 == lr&7 since o = j*16 + lr

  f32x4 acc[2][8];
#pragma unroll
  for (int i = 0; i < 2; ++i)
#pragma unroll
    for (int j = 0; j < 8; ++j) acc[i][j] = {0.f, 0.f, 0.f, 0.f};

#pragma unroll 2
  for (int kk = 0; kk < 8; ++kk) {
    const ushort* src = (kk < 4) ? mean_io : h;
    const int kb = (kk & 3) * 32 + lq * 8;
    s16x8 a0 = *(const s16x8*)(src + (size_t)(nodebase + lr) * 128 + kb);
    s16x8 a1 = *(const s16x8*)(src + (size_t)(nodebase + 16 + lr) * 128 + kb);
    const int ks = (kk * 4 + lq) ^ swz;
#pragma unroll
    for (int j = 0; j < 8; ++j) {
      int o = j * 16 + lr;
      s16x8 wf = *(const s16x8*)((const char*)Wlds + o * 512 + (ks << 4));
      acc[0][j] = __builtin_amdgcn_mfma_f32_16x16x32_bf16(wf, a0, acc[0][j], 0, 0, 0);
      acc[1][j] = __builtin_amdgcn_mfma_f32_16x16x32_bf16(wf, a1, acc[1][j], 0, 0, 0);
    }
  }

#pragma unroll
  for (int i = 0; i < 2; ++i) {
    int node = nodebase + i * 16 + lr;
    if (node < kN) {
#pragma unroll
      for (int j = 0; j < 8; ++j) {
        int o = j * 16 + lq * 4;
        float4 bv = *(const float4*)(bl + o);
        ushort4 r;
        r.x = bf16rne(fmaxf(acc[i][j][0] + bv.x, 0.f));
        r.y = bf16rne(fmaxf(acc[i][j][1] + bv.y, 0.f));
        r.z = bf16rne(fmaxf(acc[i][j][2] + bv.z, 0.f));
        r.w = bf16rne(fmaxf(acc[i][j][3] + bv.w, 0.f));
        *(ushort4*)(mean_io + (size_t)node * 128 + o) = r;
      }
    }
  }
}

// ---------------- Pooling ----------------

__device__ inline int lbound(const int* __restrict__ a, int key) {
  int lo = 0, hi = kN;
  while (lo < hi) {
    int mid = (lo + hi) >> 1;
    if (a[mid] < key) lo = mid + 1; else hi = mid;
  }
  return lo;
}

__global__ __launch_bounds__(128) void pool_kernel(const ushort* __restrict__ h,
                                                   const int* __restrict__ batch,
                                                   float* __restrict__ comb_raw,
                                                   int base) {
  int gb = blockIdx.x;
  int graph = gb >> 3;
  int chunk = gb & 7;
  int t = threadIdx.x;
  int s = lbound(batch, graph);
  int e = lbound(batch, graph + 1);
  int len = e - s;
  int c0 = s + (int)((long long)len * chunk / 8);
  int c1 = s + (int)((long long)len * (chunk + 1) / 8);
  float acc = 0.f;
  for (int n = c0; n < c1; ++n)
    acc += __builtin_bit_cast(float, (uint)h[(size_t)n * 128 + t] << 16);
  atomicAdd(&comb_raw[graph * 256 + base + t], acc);
}

// ---------------- Heads (fp32) ----------------

__global__ __launch_bounds__(64) void head_kernel(
    const float* __restrict__ comb_raw, const int* __restrict__ batch,
    const float* __restrict__ gf,
    const float* __restrict__ neg, const float* __restrict__ neb,
    const float* __restrict__ fc1W, const float* __restrict__ fc1b,
    const float* __restrict__ bn1g, const float* __restrict__ bn1b,
    const float* __restrict__ fc2W, const float* __restrict__ fc2b,
    const float* __restrict__ fc3aW, const float* __restrict__ fc3ab,
    const float* __restrict__ fc3bW, const float* __restrict__ fc3bb,
    const float* __restrict__ ncg, const float* __restrict__ ncb,
    float* __restrict__ out) {
  const int b = blockIdx.x;
  const int lane = threadIdx.x;
  int s = lbound(batch, b);
  int e = lbound(batch, b + 1);
  float cntf = fmaxf((float)(e - s), 1.0f);

  __shared__ float comb[256];
  __shared__ float x3[261];

  for (int j = lane; j < 256; j += 64)
    comb[j] = neg[j] * ((comb_raw[b * 256 + j] / cntf) * kInvBN) + neb[j];
  __syncthreads();

  float g1 = gf[b * 5 + 1], g2 = gf[b * 5 + 2], g3 = gf[b * 5 + 3], g4 = gf[b * 5 + 4];

  for (int o = 0; o < 16; o++) {
    const float* w = &fc1W[o * 257];
    float p = 0.f;
    for (int j = lane; j < 256; j += 64) p += comb[j] * w[j];
    for (int m = 32; m; m >>= 1) p += __shfl_xor(p, m, 64);
    float z = p + w[256] * g4 + fc1b[o];
    z = fmaxf(z, 0.f);
    float r = bn1g[o] * (z * kInvBN) + bn1b[o];
    if (lane == 0) out[b * 16 + o] = r;
  }

  float r2[2];
  for (int o = 0; o < 2; o++) {
    const float* w = &fc2W[o * 259];
    float p = 0.f;
    for (int j = lane; j < 256; j += 64) p += comb[j] * w[j];
    for (int m = 32; m; m >>= 1) p += __shfl_xor(p, m, 64);
    float z = p + w[256] * g2 + w[257] * g3 + w[258] * g4 + fc2b[o];
    r2[o] = fmaxf(z, 0.f);
    if (lane == 0) out[2048 + b * 2 + o] = r2[o];
  }
  int pred = (r2[1] > r2[0]) ? 1 : 0;

  for (int j = lane; j < 261; j += 64) {
    float v;
    if (j < 256) v = comb[j];
    else if (j == 256) v = g2;
    else if (j == 257) v = g1;
    else if (j == 258) v = g2;
    else if (j == 259) v = g3;
    else v = g4;
    x3[j] = ncg[j] * (v * kInvBN) + ncb[j];
  }
  __syncthreads();

  for (int o = 0; o < 4; o++) {
    const float* w = &fc3aW[o * 261];
    float p = 0.f;
    for (int j = lane; j < 261; j += 64) p += x3[j] * w[j];
    for (int m = 32; m; m >>= 1) p += __shfl_xor(p, m, 64);
    float v = p + fc3ab[o];
    if (lane == 0) out[2304 + b * 9 + o] = (pred == 0) ? v : 0.f;
  }
  for (int o = 0; o < 5; o++) {
    const float* w = &fc3bW[o * 261];
    float p = 0.f;
    for (int j = lane; j < 261; j += 64) p += x3[j] * w[j];
    for (int m = 32; m; m >>= 1) p += __shfl_xor(p, m, 64);
    float v = p + fc3bb[o];
    if (lane == 0) out[2304 + b * 9 + 4 + o] = (pred == 1) ? v : 0.f;
  }
}

// ---------------- Launch ----------------

extern "C" void kernel_launch(void* const* d_in, const int* in_sizes, int n_in,
                              void* d_out, int out_size, void* d_ws, size_t ws_size,
                              hipStream_t stream) {
  (void)in_sizes; (void)n_in; (void)out_size; (void)ws_size;
  const float* x   = (const float*)d_in[0];
  const int* ei    = (const int*)d_in[1];
  const int* ed    = (const int*)d_in[2];
  const int* batch = (const int*)d_in[3];
  const float* gf  = (const float*)d_in[4];

  char* ws = (char*)d_ws;
  auto carve = [&](size_t bytes) -> void* {
    void* p = ws;
    ws += (bytes + 255) & ~(size_t)255;
    return p;
  };
  int* cnt        = (int*)carve(2 * kN * sizeof(int));
  int* off        = (int*)carve(2 * kN * sizeof(int));
  int* cursor     = (int*)carve(2 * kN * sizeof(int));
  int* bsum       = (int*)carve(1024);
  int* csr        = (int*)carve(kE * sizeof(int));
  float* inv      = (float*)carve(2 * kN * sizeof(float));
  float* comb_raw = (float*)carve(kB * 256 * sizeof(float));
  ushort* xb      = (ushort*)carve((size_t)kNpad * 128 * 2);
  ushort* buf0    = (ushort*)carve((size_t)kNpad * 128 * 2);
  ushort* buf1    = (ushort*)carve((size_t)kNpad * 128 * 2);
  ushort* Wb      = (ushort*)carve(6 * 128 * 256 * 2);

  hipMemsetAsync(cnt, 0, 2 * kN * sizeof(int), stream);
  hipMemsetAsync(cursor, 0, 2 * kN * sizeof(int), stream);
  hipMemsetAsync(comb_raw, 0, kB * 256 * sizeof(float), stream);

  // precompute conversions (independent of CSR)
  xconv_kernel<<<(kNpad * 128 / 4 + 255) / 256, 256, 0, stream>>>(x, xb);
  for (int L = 0; L < 6; ++L) {
    wprep_kernel<<<128, 256, 0, stream>>>((const float*)d_in[6 + 3 * L],
                                          (const float*)d_in[6 + 3 * L + 2],
                                          Wb + (size_t)L * 32768);
  }

  count_kernel<<<(kE + 255) / 256, 256, 0, stream>>>(ei, ed, cnt);
  constexpr int M = 2 * kN;
  constexpr int NB = (M + 1023) / 1024;
  scan1_kernel<<<NB, 256, 0, stream>>>(cnt, off, bsum, M);
  scan2_kernel<<<1, 256, 0, stream>>>(bsum, NB);
  scan3_kernel<<<NB, 256, 0, stream>>>(off, bsum, M);
  fill_kernel<<<(kE + 255) / 256, 256, 0, stream>>>(ei, ed, off, cursor, csr);
  inv_kernel<<<(M + 255) / 256, 256, 0, stream>>>(cnt, inv);

  auto aggL = [&](const ushort* h, ushort* a, int dirbase) {
    agg_kernel<<<kN / 4, 256, 0, stream>>>(h, a, off, cnt, csr, inv, dirbase);
  };
  auto layerL = [&](ushort* a, const ushort* h, int L) {
    layer_mfma_kernel<<<kNpad / 128, 256, 0, stream>>>(
        a, h, Wb + (size_t)L * 32768, (const float*)d_in[6 + 3 * L + 1]);
  };

  // pre chain (dir bucket base 0)
  aggL(xb, buf0, 0);     layerL(buf0, xb, 0);
  aggL(buf0, buf1, 0);   layerL(buf1, buf0, 1);
  aggL(buf1, buf0, 0);   layerL(buf0, buf1, 2);
  pool_kernel<<<kB * 8, 128, 0, stream>>>(buf0, batch, comb_raw, 0);

  // suc chain (dir bucket base kN)
  aggL(xb, buf1, kN);    layerL(buf1, xb, 3);
  aggL(buf1, buf0, kN);  layerL(buf0, buf1, 4);
  aggL(buf0, buf1, kN);  layerL(buf1, buf0, 5);
  pool_kernel<<<kB * 8, 128, 0, stream>>>(buf1, batch, comb_raw, 128);

  head_kernel<<<kB, 64, 0, stream>>>(
      comb_raw, batch, gf,
      (const float*)d_in[24], (const float*)d_in[25],
      (const float*)d_in[26], (const float*)d_in[27],
      (const float*)d_in[28], (const float*)d_in[29],
      (const float*)d_in[30], (const float*)d_in[31],
      (const float*)d_in[32], (const float*)d_in[33],
      (const float*)d_in[34], (const float*)d_in[35],
      (const float*)d_in[36], (const float*)d_in[37],
      (float*)d_out);
}

// Round 3
// 541.137 us; speedup vs baseline: 2.7698x; 1.3189x over previous
//
#include <hip/hip_runtime.h>

constexpr int kN = 100000;
constexpr int kNpad = 100096;      // 782 * 128
constexpr int kE = 800000;
constexpr int kB = 128;
constexpr float kInvBN = 0.99999500003749968f; // 1/sqrt(1+1e-5)

typedef short s16x8 __attribute__((ext_vector_type(8)));
typedef float f32x4 __attribute__((ext_vector_type(4)));

__device__ inline ushort bf16rne(float f) {
  uint u = __builtin_bit_cast(uint, f);
  u += 0x7fffu + ((u >> 16) & 1u);
  return (ushort)(u >> 16);
}
__device__ inline float bflo(uint v) { return __builtin_bit_cast(float, v << 16); }
__device__ inline float bfhi(uint v) { return __builtin_bit_cast(float, v & 0xffff0000u); }

// ---------------- CSR build ----------------

__global__ __launch_bounds__(256) void count_kernel(const int* __restrict__ ei,
                                                    const int* __restrict__ ed,
                                                    int* __restrict__ cnt) {
  int e = blockIdx.x * 256 + threadIdx.x;
  if (e >= kE) return;
  atomicAdd(&cnt[ed[e] * kN + ei[kE + e]], 1);
}

__global__ __launch_bounds__(256) void scan1_kernel(const int* __restrict__ in,
                                                    int* __restrict__ out,
                                                    int* __restrict__ bsum, int M) {
  __shared__ int s[256];
  int t = threadIdx.x;
  int idx = blockIdx.x * 1024 + t * 4;
  int4 v = {0, 0, 0, 0};
  if (idx < M) v = *(const int4*)&in[idx];
  int tsum = v.x + v.y + v.z + v.w;
  s[t] = tsum;
  __syncthreads();
  for (int d = 1; d < 256; d <<= 1) {
    int tmp = (t >= d) ? s[t - d] : 0;
    __syncthreads();
    s[t] += tmp;
    __syncthreads();
  }
  int excl = s[t] - tsum;
  if (idx < M) {
    int4 o;
    o.x = excl; o.y = excl + v.x; o.z = o.y + v.y; o.w = o.z + v.z;
    *(int4*)&out[idx] = o;
  }
  if (t == 255) bsum[blockIdx.x] = s[255];
}

__global__ __launch_bounds__(256) void scan2_kernel(int* __restrict__ bsum, int nb) {
  __shared__ int s[256];
  int t = threadIdx.x;
  int v = (t < nb) ? bsum[t] : 0;
  s[t] = v;
  __syncthreads();
  for (int d = 1; d < 256; d <<= 1) {
    int tmp = (t >= d) ? s[t - d] : 0;
    __syncthreads();
    s[t] += tmp;
    __syncthreads();
  }
  if (t < nb) bsum[t] = s[t] - v;
}

__global__ __launch_bounds__(256) void scan3_kernel(int* __restrict__ out,
                                                    const int* __restrict__ bsum, int M) {
  int idx = blockIdx.x * 1024 + threadIdx.x * 4;
  int add = bsum[blockIdx.x];
  if (idx < M) {
    int4 o = *(int4*)&out[idx];
    o.x += add; o.y += add; o.z += add; o.w += add;
    *(int4*)&out[idx] = o;
  }
}

__global__ __launch_bounds__(256) void fill_kernel(const int* __restrict__ ei,
                                                   const int* __restrict__ ed,
                                                   const int* __restrict__ off,
                                                   int* __restrict__ cursor,
                                                   int* __restrict__ csr) {
  int e = blockIdx.x * 256 + threadIdx.x;
  if (e >= kE) return;
  int bkt = ed[e] * kN + ei[kE + e];
  int pos = atomicAdd(&cursor[bkt], 1);
  csr[off[bkt] + pos] = ei[e];
}

// graph start offsets from sorted batch
__global__ __launch_bounds__(256) void gstart_kernel(const int* __restrict__ batch,
                                                     int* __restrict__ gstart) {
  int n = blockIdx.x * 256 + threadIdx.x;
  if (n >= kN) return;
  int b = batch[n];
  int bprev = (n == 0) ? -1 : batch[n - 1];
  for (int g = bprev + 1; g <= b; ++g) gstart[g] = n;
  if (n == kN - 1)
    for (int g = b + 1; g <= kB; ++g) gstart[g] = kN;
}

// ---------------- precompute: x -> bf16 (padded), weights -> packed bf16 ----------------

__global__ __launch_bounds__(256) void xconv_kernel(const float* __restrict__ x,
                                                    ushort* __restrict__ xb) {
  int gid = blockIdx.x * 256 + threadIdx.x;
  int i4 = gid * 4;
  if (i4 >= kNpad * 128) return;
  ushort4 r;
  if (i4 < kN * 128) {
    float4 v = *(const float4*)&x[i4];
    r.x = bf16rne(v.x); r.y = bf16rne(v.y); r.z = bf16rne(v.z); r.w = bf16rne(v.w);
  } else {
    r.x = r.y = r.z = r.w = 0;
  }
  *(ushort4*)&xb[i4] = r;
}

struct WPtrs { const float* Wl[6]; const float* Wr[6]; };

__global__ __launch_bounds__(256) void wprep_kernel(WPtrs p, ushort* __restrict__ Wb) {
  int id = blockIdx.x * 256 + threadIdx.x; // L*32768 + o*256 + k
  int L = id >> 15;
  int o = (id >> 8) & 127, k = id & 255;
  const float* src = (k < 128) ? p.Wl[L] : p.Wr[L];
  Wb[id] = bf16rne(src[o * 128 + (k & 127)]);
}

// ---------------- Aggregation: 16-lane group per node, 16B gathers ----------------

__global__ __launch_bounds__(256) void agg_kernel(const ushort* __restrict__ h,
                                                  ushort* __restrict__ aggout,
                                                  const int* __restrict__ off,
                                                  const int* __restrict__ cnt,
                                                  const int* __restrict__ csr,
                                                  int dirbase) {
  int gid = blockIdx.x * 256 + threadIdx.x;
  int node = gid >> 4;
  int lane = gid & 15;
  if (node >= kN) return;
  int bkt = dirbase + node;
  int s = off[bkt];
  int c = cnt[bkt];
  float acc[8] = {0.f, 0.f, 0.f, 0.f, 0.f, 0.f, 0.f, 0.f};
  const ushort* hp = h + lane * 8;
  for (int e = 0; e < c; ++e) {
    int src = csr[s + e];
    uint4 v = *(const uint4*)(hp + (size_t)src * 128);
    acc[0] += bflo(v.x); acc[1] += bfhi(v.x);
    acc[2] += bflo(v.y); acc[3] += bfhi(v.y);
    acc[4] += bflo(v.z); acc[5] += bfhi(v.z);
    acc[6] += bflo(v.w); acc[7] += bfhi(v.w);
  }
  float iv = 1.0f / fmaxf((float)c, 1.0f);
  uint4 r;
  r.x = (uint)bf16rne(acc[0] * iv) | ((uint)bf16rne(acc[1] * iv) << 16);
  r.y = (uint)bf16rne(acc[2] * iv) | ((uint)bf16rne(acc[3] * iv) << 16);
  r.z = (uint)bf16rne(acc[4] * iv) | ((uint)bf16rne(acc[5] * iv) << 16);
  r.w = (uint)bf16rne(acc[6] * iv) | ((uint)bf16rne(acc[7] * iv) << 16);
  *(uint4*)(aggout + (size_t)node * 128 + lane * 8) = r;
}

// ---------------- MFMA layer (unchanged, verified) ----------------

__global__ __launch_bounds__(256) void layer_mfma_kernel(
    ushort* __restrict__ mean_io, const ushort* __restrict__ h,
    const ushort* __restrict__ Wb, const float* __restrict__ bl) {
  __shared__ ushort Wlds[128 * 256];

  const int t = threadIdx.x;
#pragma unroll
  for (int it = 0; it < 16; ++it) {
    int u = t + 256 * it;
    int o = u >> 5, b = u & 31;
    uint4 v = *(const uint4*)(Wb + (size_t)u * 8);
    *(uint4*)((char*)Wlds + o * 512 + ((b ^ (o & 7)) << 4)) = v;
  }
  __syncthreads();

  const int w = t >> 6;
  const int l = t & 63;
  const int lr = l & 15;
  const int lq = l >> 4;
  const int nodebase = blockIdx.x * 128 + w * 32;
  const int swz = lr & 7;

  f32x4 acc[2][8];
#pragma unroll
  for (int i = 0; i < 2; ++i)
#pragma unroll
    for (int j = 0; j < 8; ++j) acc[i][j] = {0.f, 0.f, 0.f, 0.f};

#pragma unroll 2
  for (int kk = 0; kk < 8; ++kk) {
    const ushort* src = (kk < 4) ? mean_io : h;
    const int kb = (kk & 3) * 32 + lq * 8;
    s16x8 a0 = *(const s16x8*)(src + (size_t)(nodebase + lr) * 128 + kb);
    s16x8 a1 = *(const s16x8*)(src + (size_t)(nodebase + 16 + lr) * 128 + kb);
    const int ks = (kk * 4 + lq) ^ swz;
#pragma unroll
    for (int j = 0; j < 8; ++j) {
      int o = j * 16 + lr;
      s16x8 wf = *(const s16x8*)((const char*)Wlds + o * 512 + (ks << 4));
      acc[0][j] = __builtin_amdgcn_mfma_f32_16x16x32_bf16(wf, a0, acc[0][j], 0, 0, 0);
      acc[1][j] = __builtin_amdgcn_mfma_f32_16x16x32_bf16(wf, a1, acc[1][j], 0, 0, 0);
    }
  }

#pragma unroll
  for (int i = 0; i < 2; ++i) {
    int node = nodebase + i * 16 + lr;
    if (node < kN) {
#pragma unroll
      for (int j = 0; j < 8; ++j) {
        int o = j * 16 + lq * 4;
        float4 bv = *(const float4*)(bl + o);
        ushort4 r;
        r.x = bf16rne(fmaxf(acc[i][j][0] + bv.x, 0.f));
        r.y = bf16rne(fmaxf(acc[i][j][1] + bv.y, 0.f));
        r.z = bf16rne(fmaxf(acc[i][j][2] + bv.z, 0.f));
        r.w = bf16rne(fmaxf(acc[i][j][3] + bv.w, 0.f));
        *(ushort4*)(mean_io + (size_t)node * 128 + o) = r;
      }
    }
  }
}

// ---------------- Pooling: one block per graph, no atomics ----------------

__global__ __launch_bounds__(256) void pool_kernel(const ushort* __restrict__ h,
                                                   const int* __restrict__ gstart,
                                                   float* __restrict__ comb_raw,
                                                   int base) {
  __shared__ float part[4 * 128];
  int b = blockIdx.x;
  int t = threadIdx.x;
  int w = t >> 6;
  int lane = t & 63;
  int s = gstart[b];
  int e = gstart[b + 1];
  float ax = 0.f, ay = 0.f;
  for (int n = s + w; n < e; n += 4) {
    uint v = *(const uint*)(h + (size_t)n * 128 + lane * 2);
    ax += bflo(v);
    ay += bfhi(v);
  }
  part[w * 128 + lane * 2] = ax;
  part[w * 128 + lane * 2 + 1] = ay;
  __syncthreads();
  if (t < 128) {
    float v = part[t] + part[128 + t] + part[256 + t] + part[384 + t];
    comb_raw[b * 256 + base + t] = v;
  }
}

// ---------------- Heads: 256 threads, LDS-staged weights, parallel dots ----------------

__global__ __launch_bounds__(256) void head_kernel(
    const float* __restrict__ comb_raw, const int* __restrict__ gstart,
    const float* __restrict__ gf,
    const float* __restrict__ neg, const float* __restrict__ neb,
    const float* __restrict__ fc1W, const float* __restrict__ fc1b,
    const float* __restrict__ bn1g, const float* __restrict__ bn1b,
    const float* __restrict__ fc2W, const float* __restrict__ fc2b,
    const float* __restrict__ fc3aW, const float* __restrict__ fc3ab,
    const float* __restrict__ fc3bW, const float* __restrict__ fc3bb,
    const float* __restrict__ ncg, const float* __restrict__ ncb,
    float* __restrict__ out) {
  // LDS: fc1W 4112 | fc2W 518 | fc3aW 1044 | fc3bW 1305
  __shared__ float wlds[6979];
  __shared__ float comb[256];
  __shared__ float x3[261];
  __shared__ float r2s[2];

  const int b = blockIdx.x;
  const int t = threadIdx.x;

  for (int i = t; i < 4112; i += 256) wlds[i] = fc1W[i];
  for (int i = t; i < 518; i += 256) wlds[4112 + i] = fc2W[i];
  for (int i = t; i < 1044; i += 256) wlds[4630 + i] = fc3aW[i];
  for (int i = t; i < 1305; i += 256) wlds[5674 + i] = fc3bW[i];

  float cntf = fmaxf((float)(gstart[b + 1] - gstart[b]), 1.0f);
  if (t < 256) comb[t] = neg[t] * ((comb_raw[b * 256 + t] / cntf) * kInvBN) + neb[t];
  __syncthreads();

  float g1 = gf[b * 5 + 1], g2 = gf[b * 5 + 2], g3 = gf[b * 5 + 3], g4 = gf[b * 5 + 4];
  const int g = t >> 3, l8 = t & 7;

  // Round A: fc1 (16 dots) + fc2 (2 dots), all in parallel
  {
    float p = 0.f;
    if (g < 16) {
      const float* w = &wlds[g * 257];
      for (int j = l8; j < 256; j += 8) p += comb[j] * w[j];
    } else if (g < 18) {
      const float* w = &wlds[4112 + (g - 16) * 259];
      for (int j = l8; j < 256; j += 8) p += comb[j] * w[j];
    }
    p += __shfl_xor(p, 1);
    p += __shfl_xor(p, 2);
    p += __shfl_xor(p, 4);
    if (l8 == 0) {
      if (g < 16) {
        float z = fmaxf(p + wlds[g * 257 + 256] * g4 + fc1b[g], 0.f);
        out[b * 16 + g] = bn1g[g] * (z * kInvBN) + bn1b[g];
      } else if (g < 18) {
        int o = g - 16;
        const float* w = &wlds[4112 + o * 259];
        float z = fmaxf(p + w[256] * g2 + w[257] * g3 + w[258] * g4 + fc2b[o], 0.f);
        out[2048 + b * 2 + o] = z;
        r2s[o] = z;
      }
    }
  }
  // x3 = bn([comb, g2, g1, g2, g3, g4])
  for (int j = t; j < 261; j += 256) {
    float v;
    if (j < 256) v = comb[j];
    else if (j == 256) v = g2;
    else if (j == 257) v = g1;
    else if (j == 258) v = g2;
    else if (j == 259) v = g3;
    else v = g4;
    x3[j] = ncg[j] * (v * kInvBN) + ncb[j];
  }
  __syncthreads();
  int pred = (r2s[1] > r2s[0]) ? 1 : 0;

  // Round B: fc3a (4) + fc3b (5)
  {
    float p = 0.f;
    if (g < 4) {
      const float* w = &wlds[4630 + g * 261];
      for (int j = l8; j < 261; j += 8) p += x3[j] * w[j];
    } else if (g < 9) {
      const float* w = &wlds[5674 + (g - 4) * 261];
      for (int j = l8; j < 261; j += 8) p += x3[j] * w[j];
    }
    p += __shfl_xor(p, 1);
    p += __shfl_xor(p, 2);
    p += __shfl_xor(p, 4);
    if (l8 == 0) {
      if (g < 4) {
        float v = p + fc3ab[g];
        out[2304 + b * 9 + g] = (pred == 0) ? v : 0.f;
      } else if (g < 9) {
        int o = g - 4;
        float v = p + fc3bb[o];
        out[2304 + b * 9 + 4 + o] = (pred == 1) ? v : 0.f;
      }
    }
  }
}

// ---------------- Launch ----------------

extern "C" void kernel_launch(void* const* d_in, const int* in_sizes, int n_in,
                              void* d_out, int out_size, void* d_ws, size_t ws_size,
                              hipStream_t stream) {
  (void)in_sizes; (void)n_in; (void)out_size; (void)ws_size;
  const float* x   = (const float*)d_in[0];
  const int* ei    = (const int*)d_in[1];
  const int* ed    = (const int*)d_in[2];
  const int* batch = (const int*)d_in[3];
  const float* gf  = (const float*)d_in[4];

  char* ws = (char*)d_ws;
  auto carve = [&](size_t bytes) -> void* {
    void* p = ws;
    ws += (bytes + 255) & ~(size_t)255;
    return p;
  };
  int* cnt        = (int*)carve(2 * kN * sizeof(int));
  int* off        = (int*)carve(2 * kN * sizeof(int));
  int* cursor     = (int*)carve(2 * kN * sizeof(int));
  int* bsum       = (int*)carve(1024);
  int* gstart     = (int*)carve((kB + 1) * sizeof(int));
  int* csr        = (int*)carve(kE * sizeof(int));
  float* comb_raw = (float*)carve(kB * 256 * sizeof(float));
  ushort* xb      = (ushort*)carve((size_t)kNpad * 128 * 2);
  ushort* buf0    = (ushort*)carve((size_t)kNpad * 128 * 2);
  ushort* buf1    = (ushort*)carve((size_t)kNpad * 128 * 2);
  ushort* Wb      = (ushort*)carve(6 * 128 * 256 * 2);

  hipMemsetAsync(cnt, 0, 2 * kN * sizeof(int), stream);
  hipMemsetAsync(cursor, 0, 2 * kN * sizeof(int), stream);

  xconv_kernel<<<(kNpad * 128 / 4 + 255) / 256, 256, 0, stream>>>(x, xb);
  WPtrs wp;
  for (int L = 0; L < 6; ++L) {
    wp.Wl[L] = (const float*)d_in[6 + 3 * L];
    wp.Wr[L] = (const float*)d_in[6 + 3 * L + 2];
  }
  wprep_kernel<<<768, 256, 0, stream>>>(wp, Wb);

  count_kernel<<<(kE + 255) / 256, 256, 0, stream>>>(ei, ed, cnt);
  constexpr int M = 2 * kN;
  constexpr int NB = (M + 1023) / 1024;
  scan1_kernel<<<NB, 256, 0, stream>>>(cnt, off, bsum, M);
  scan2_kernel<<<1, 256, 0, stream>>>(bsum, NB);
  scan3_kernel<<<NB, 256, 0, stream>>>(off, bsum, M);
  fill_kernel<<<(kE + 255) / 256, 256, 0, stream>>>(ei, ed, off, cursor, csr);
  gstart_kernel<<<(kN + 255) / 256, 256, 0, stream>>>(batch, gstart);

  auto aggL = [&](const ushort* h, ushort* a, int dirbase) {
    agg_kernel<<<kN * 16 / 256, 256, 0, stream>>>(h, a, off, cnt, csr, dirbase);
  };
  auto layerL = [&](ushort* a, const ushort* h, int L) {
    layer_mfma_kernel<<<kNpad / 128, 256, 0, stream>>>(
        a, h, Wb + (size_t)L * 32768, (const float*)d_in[6 + 3 * L + 1]);
  };

  // pre chain (dir bucket base 0)
  aggL(xb, buf0, 0);     layerL(buf0, xb, 0);
  aggL(buf0, buf1, 0);   layerL(buf1, buf0, 1);
  aggL(buf1, buf0, 0);   layerL(buf0, buf1, 2);
  pool_kernel<<<kB, 256, 0, stream>>>(buf0, gstart, comb_raw, 0);

  // suc chain (dir bucket base kN)
  aggL(xb, buf1, kN);    layerL(buf1, xb, 3);
  aggL(buf1, buf0, kN);  layerL(buf0, buf1, 4);
  aggL(buf0, buf1, kN);  layerL(buf1, buf0, 5);
  pool_kernel<<<kB, 256, 0, stream>>>(buf1, gstart, comb_raw, 128);

  head_kernel<<<kB, 256, 0, stream>>>(
      comb_raw, gstart, gf,
      (const float*)d_in[24], (const float*)d_in[25],
      (const float*)d_in[26], (const float*)d_in[27],
      (const float*)d_in[28], (const float*)d_in[29],
      (const float*)d_in[30], (const float*)d_in[31],
      (const float*)d_in[32], (const float*)d_in[33],
      (const float*)d_in[34], (const float*)d_in[35],
      (const float*)d_in[36], (const float*)d_in[37],
      (float*)d_out);
}

// Round 4
// 428.243 us; speedup vs baseline: 3.5000x; 1.2636x over previous
//
#include <hip/hip_runtime.h>

constexpr int kN = 100000;
constexpr int kNpad = 100096;      // 782 * 128
constexpr int kE = 800000;
constexpr int kB = 128;
constexpr float kInvBN = 0.99999500003749968f; // 1/sqrt(1+1e-5)

typedef short s16x8 __attribute__((ext_vector_type(8)));
typedef float f32x4 __attribute__((ext_vector_type(4)));

__device__ inline ushort bf16rne(float f) {
  uint u = __builtin_bit_cast(uint, f);
  u += 0x7fffu + ((u >> 16) & 1u);
  return (ushort)(u >> 16);
}
__device__ inline float bflo(uint v) { return __builtin_bit_cast(float, v << 16); }
__device__ inline float bfhi(uint v) { return __builtin_bit_cast(float, v & 0xffff0000u); }

// ---------------- CSR build ----------------

__global__ __launch_bounds__(256) void count_kernel(const int* __restrict__ ei,
                                                    const int* __restrict__ ed,
                                                    int* __restrict__ cnt) {
  int e = blockIdx.x * 256 + threadIdx.x;
  if (e >= kE) return;
  atomicAdd(&cnt[ed[e] * kN + ei[kE + e]], 1);
}

__global__ __launch_bounds__(256) void scan1_kernel(const int* __restrict__ in,
                                                    int* __restrict__ out,
                                                    int* __restrict__ bsum, int M) {
  __shared__ int s[256];
  int t = threadIdx.x;
  int idx = blockIdx.x * 1024 + t * 4;
  int4 v = {0, 0, 0, 0};
  if (idx < M) v = *(const int4*)&in[idx];
  int tsum = v.x + v.y + v.z + v.w;
  s[t] = tsum;
  __syncthreads();
  for (int d = 1; d < 256; d <<= 1) {
    int tmp = (t >= d) ? s[t - d] : 0;
    __syncthreads();
    s[t] += tmp;
    __syncthreads();
  }
  int excl = s[t] - tsum;
  if (idx < M) {
    int4 o;
    o.x = excl; o.y = excl + v.x; o.z = o.y + v.y; o.w = o.z + v.z;
    *(int4*)&out[idx] = o;
  }
  if (t == 255) bsum[blockIdx.x] = s[255];
}

__global__ __launch_bounds__(256) void scan2_kernel(int* __restrict__ bsum, int nb) {
  __shared__ int s[256];
  int t = threadIdx.x;
  int v = (t < nb) ? bsum[t] : 0;
  s[t] = v;
  __syncthreads();
  for (int d = 1; d < 256; d <<= 1) {
    int tmp = (t >= d) ? s[t - d] : 0;
    __syncthreads();
    s[t] += tmp;
    __syncthreads();
  }
  if (t < nb) bsum[t] = s[t] - v;
}

__global__ __launch_bounds__(256) void scan3_kernel(int* __restrict__ out,
                                                    const int* __restrict__ bsum, int M) {
  int idx = blockIdx.x * 1024 + threadIdx.x * 4;
  int add = bsum[blockIdx.x];
  if (idx < M) {
    int4 o = *(int4*)&out[idx];
    o.x += add; o.y += add; o.z += add; o.w += add;
    *(int4*)&out[idx] = o;
  }
}

__global__ __launch_bounds__(256) void fill_kernel(const int* __restrict__ ei,
                                                   const int* __restrict__ ed,
                                                   const int* __restrict__ off,
                                                   int* __restrict__ cursor,
                                                   int* __restrict__ csr) {
  int e = blockIdx.x * 256 + threadIdx.x;
  if (e >= kE) return;
  int bkt = ed[e] * kN + ei[kE + e];
  int pos = atomicAdd(&cursor[bkt], 1);
  csr[off[bkt] + pos] = ei[e];
}

// graph start offsets from sorted batch
__global__ __launch_bounds__(256) void gstart_kernel(const int* __restrict__ batch,
                                                     int* __restrict__ gstart) {
  int n = blockIdx.x * 256 + threadIdx.x;
  if (n >= kN) return;
  int b = batch[n];
  int bprev = (n == 0) ? -1 : batch[n - 1];
  for (int g = bprev + 1; g <= b; ++g) gstart[g] = n;
  if (n == kN - 1)
    for (int g = b + 1; g <= kB; ++g) gstart[g] = kN;
}

// ---------------- precompute: x -> bf16 (padded), weights -> packed bf16 ----------------

__global__ __launch_bounds__(256) void xconv_kernel(const float* __restrict__ x,
                                                    ushort* __restrict__ xb) {
  int gid = blockIdx.x * 256 + threadIdx.x;
  int i4 = gid * 4;
  if (i4 >= kNpad * 128) return;
  ushort4 r;
  if (i4 < kN * 128) {
    float4 v = *(const float4*)&x[i4];
    r.x = bf16rne(v.x); r.y = bf16rne(v.y); r.z = bf16rne(v.z); r.w = bf16rne(v.w);
  } else {
    r.x = r.y = r.z = r.w = 0;
  }
  *(ushort4*)&xb[i4] = r;
}

struct WPtrs { const float* Wl[6]; const float* Wr[6]; };

__global__ __launch_bounds__(256) void wprep_kernel(WPtrs p, ushort* __restrict__ Wb) {
  int id = blockIdx.x * 256 + threadIdx.x; // L*32768 + o*256 + k
  int L = id >> 15;
  int o = (id >> 8) & 127, k = id & 255;
  const float* src = (k < 128) ? p.Wl[L] : p.Wr[L];
  Wb[id] = bf16rne(src[o * 128 + (k & 127)]);
}

// ---------------- Aggregation: 8-lane group per node, 2x16B gathers per edge ----------------

__global__ __launch_bounds__(256) void agg_kernel(const ushort* __restrict__ h,
                                                  ushort* __restrict__ aggout,
                                                  const int* __restrict__ off,
                                                  const int* __restrict__ cnt,
                                                  const int* __restrict__ csr,
                                                  int dirbase) {
  int gid = blockIdx.x * 256 + threadIdx.x;
  int node = gid >> 3;
  int lane = gid & 7;
  if (node >= kN) return;
  int bkt = dirbase + node;
  int s = off[bkt];
  int c = cnt[bkt];
  float acc[16];
#pragma unroll
  for (int i = 0; i < 16; ++i) acc[i] = 0.f;
  const ushort* hp = h + lane * 16;
  for (int e = 0; e < c; ++e) {
    int src = csr[s + e];
    uint4 v0 = *(const uint4*)(hp + (size_t)src * 128);
    uint4 v1 = *(const uint4*)(hp + (size_t)src * 128 + 8);
    acc[0] += bflo(v0.x); acc[1] += bfhi(v0.x);
    acc[2] += bflo(v0.y); acc[3] += bfhi(v0.y);
    acc[4] += bflo(v0.z); acc[5] += bfhi(v0.z);
    acc[6] += bflo(v0.w); acc[7] += bfhi(v0.w);
    acc[8] += bflo(v1.x); acc[9] += bfhi(v1.x);
    acc[10] += bflo(v1.y); acc[11] += bfhi(v1.y);
    acc[12] += bflo(v1.z); acc[13] += bfhi(v1.z);
    acc[14] += bflo(v1.w); acc[15] += bfhi(v1.w);
  }
  float iv = 1.0f / fmaxf((float)c, 1.0f);
  uint4 r0, r1;
  r0.x = (uint)bf16rne(acc[0] * iv) | ((uint)bf16rne(acc[1] * iv) << 16);
  r0.y = (uint)bf16rne(acc[2] * iv) | ((uint)bf16rne(acc[3] * iv) << 16);
  r0.z = (uint)bf16rne(acc[4] * iv) | ((uint)bf16rne(acc[5] * iv) << 16);
  r0.w = (uint)bf16rne(acc[6] * iv) | ((uint)bf16rne(acc[7] * iv) << 16);
  r1.x = (uint)bf16rne(acc[8] * iv) | ((uint)bf16rne(acc[9] * iv) << 16);
  r1.y = (uint)bf16rne(acc[10] * iv) | ((uint)bf16rne(acc[11] * iv) << 16);
  r1.z = (uint)bf16rne(acc[12] * iv) | ((uint)bf16rne(acc[13] * iv) << 16);
  r1.w = (uint)bf16rne(acc[14] * iv) | ((uint)bf16rne(acc[15] * iv) << 16);
  ushort* op = aggout + (size_t)node * 128 + lane * 16;
  *(uint4*)op = r0;
  *(uint4*)(op + 8) = r1;
}

// ---------------- MFMA layer (unchanged, verified) ----------------

__global__ __launch_bounds__(256) void layer_mfma_kernel(
    ushort* __restrict__ mean_io, const ushort* __restrict__ h,
    const ushort* __restrict__ Wb, const float* __restrict__ bl) {
  __shared__ ushort Wlds[128 * 256];

  const int t = threadIdx.x;
#pragma unroll
  for (int it = 0; it < 16; ++it) {
    int u = t + 256 * it;
    int o = u >> 5, b = u & 31;
    uint4 v = *(const uint4*)(Wb + (size_t)u * 8);
    *(uint4*)((char*)Wlds + o * 512 + ((b ^ (o & 7)) << 4)) = v;
  }
  __syncthreads();

  const int w = t >> 6;
  const int l = t & 63;
  const int lr = l & 15;
  const int lq = l >> 4;
  const int nodebase = blockIdx.x * 128 + w * 32;
  const int swz = lr & 7;

  f32x4 acc[2][8];
#pragma unroll
  for (int i = 0; i < 2; ++i)
#pragma unroll
    for (int j = 0; j < 8; ++j) acc[i][j] = {0.f, 0.f, 0.f, 0.f};

#pragma unroll 2
  for (int kk = 0; kk < 8; ++kk) {
    const ushort* src = (kk < 4) ? mean_io : h;
    const int kb = (kk & 3) * 32 + lq * 8;
    s16x8 a0 = *(const s16x8*)(src + (size_t)(nodebase + lr) * 128 + kb);
    s16x8 a1 = *(const s16x8*)(src + (size_t)(nodebase + 16 + lr) * 128 + kb);
    const int ks = (kk * 4 + lq) ^ swz;
#pragma unroll
    for (int j = 0; j < 8; ++j) {
      int o = j * 16 + lr;
      s16x8 wf = *(const s16x8*)((const char*)Wlds + o * 512 + (ks << 4));
      acc[0][j] = __builtin_amdgcn_mfma_f32_16x16x32_bf16(wf, a0, acc[0][j], 0, 0, 0);
      acc[1][j] = __builtin_amdgcn_mfma_f32_16x16x32_bf16(wf, a1, acc[1][j], 0, 0, 0);
    }
  }

#pragma unroll
  for (int i = 0; i < 2; ++i) {
    int node = nodebase + i * 16 + lr;
    if (node < kN) {
#pragma unroll
      for (int j = 0; j < 8; ++j) {
        int o = j * 16 + lq * 4;
        float4 bv = *(const float4*)(bl + o);
        ushort4 r;
        r.x = bf16rne(fmaxf(acc[i][j][0] + bv.x, 0.f));
        r.y = bf16rne(fmaxf(acc[i][j][1] + bv.y, 0.f));
        r.z = bf16rne(fmaxf(acc[i][j][2] + bv.z, 0.f));
        r.w = bf16rne(fmaxf(acc[i][j][3] + bv.w, 0.f));
        *(ushort4*)(mean_io + (size_t)node * 128 + o) = r;
      }
    }
  }
}

// ---------------- Pooling: 16 chunks per graph, LDS partial + atomic flush ----------------

__global__ __launch_bounds__(256) void pool_kernel(const ushort* __restrict__ h,
                                                   const int* __restrict__ gstart,
                                                   float* __restrict__ comb_raw,
                                                   int base) {
  __shared__ float part[4 * 128];
  int gb = blockIdx.x;
  int graph = gb >> 4;
  int chunk = gb & 15;
  int t = threadIdx.x;
  int slice = t >> 6;   // 0..3
  int col = t & 63;     // uint column (2 channels)
  int s = gstart[graph];
  int e = gstart[graph + 1];
  int len = e - s;
  int c0 = s + (int)((long long)len * chunk / 16);
  int c1 = s + (int)((long long)len * (chunk + 1) / 16);
  float ax = 0.f, ay = 0.f;
  for (int n = c0 + slice; n < c1; n += 4) {
    uint v = *(const uint*)(h + (size_t)n * 128 + col * 2);
    ax += bflo(v);
    ay += bfhi(v);
  }
  part[slice * 128 + col * 2] = ax;
  part[slice * 128 + col * 2 + 1] = ay;
  __syncthreads();
  if (t < 128) {
    float v = part[t] + part[128 + t] + part[256 + t] + part[384 + t];
    atomicAdd(&comb_raw[graph * 256 + base + t], v);
  }
}

// ---------------- Heads: 256 threads, LDS-staged weights, parallel dots ----------------

__global__ __launch_bounds__(256) void head_kernel(
    const float* __restrict__ comb_raw, const int* __restrict__ gstart,
    const float* __restrict__ gf,
    const float* __restrict__ neg, const float* __restrict__ neb,
    const float* __restrict__ fc1W, const float* __restrict__ fc1b,
    const float* __restrict__ bn1g, const float* __restrict__ bn1b,
    const float* __restrict__ fc2W, const float* __restrict__ fc2b,
    const float* __restrict__ fc3aW, const float* __restrict__ fc3ab,
    const float* __restrict__ fc3bW, const float* __restrict__ fc3bb,
    const float* __restrict__ ncg, const float* __restrict__ ncb,
    float* __restrict__ out) {
  __shared__ float wlds[6979];
  __shared__ float comb[256];
  __shared__ float x3[261];
  __shared__ float r2s[2];

  const int b = blockIdx.x;
  const int t = threadIdx.x;

  for (int i = t; i < 4112; i += 256) wlds[i] = fc1W[i];
  for (int i = t; i < 518; i += 256) wlds[4112 + i] = fc2W[i];
  for (int i = t; i < 1044; i += 256) wlds[4630 + i] = fc3aW[i];
  for (int i = t; i < 1305; i += 256) wlds[5674 + i] = fc3bW[i];

  float cntf = fmaxf((float)(gstart[b + 1] - gstart[b]), 1.0f);
  if (t < 256) comb[t] = neg[t] * ((comb_raw[b * 256 + t] / cntf) * kInvBN) + neb[t];
  __syncthreads();

  float g1 = gf[b * 5 + 1], g2 = gf[b * 5 + 2], g3 = gf[b * 5 + 3], g4 = gf[b * 5 + 4];
  const int g = t >> 3, l8 = t & 7;

  {
    float p = 0.f;
    if (g < 16) {
      const float* w = &wlds[g * 257];
      for (int j = l8; j < 256; j += 8) p += comb[j] * w[j];
    } else if (g < 18) {
      const float* w = &wlds[4112 + (g - 16) * 259];
      for (int j = l8; j < 256; j += 8) p += comb[j] * w[j];
    }
    p += __shfl_xor(p, 1);
    p += __shfl_xor(p, 2);
    p += __shfl_xor(p, 4);
    if (l8 == 0) {
      if (g < 16) {
        float z = fmaxf(p + wlds[g * 257 + 256] * g4 + fc1b[g], 0.f);
        out[b * 16 + g] = bn1g[g] * (z * kInvBN) + bn1b[g];
      } else if (g < 18) {
        int o = g - 16;
        const float* w = &wlds[4112 + o * 259];
        float z = fmaxf(p + w[256] * g2 + w[257] * g3 + w[258] * g4 + fc2b[o], 0.f);
        out[2048 + b * 2 + o] = z;
        r2s[o] = z;
      }
    }
  }
  for (int j = t; j < 261; j += 256) {
    float v;
    if (j < 256) v = comb[j];
    else if (j == 256) v = g2;
    else if (j == 257) v = g1;
    else if (j == 258) v = g2;
    else if (j == 259) v = g3;
    else v = g4;
    x3[j] = ncg[j] * (v * kInvBN) + ncb[j];
  }
  __syncthreads();
  int pred = (r2s[1] > r2s[0]) ? 1 : 0;

  {
    float p = 0.f;
    if (g < 4) {
      const float* w = &wlds[4630 + g * 261];
      for (int j = l8; j < 261; j += 8) p += x3[j] * w[j];
    } else if (g < 9) {
      const float* w = &wlds[5674 + (g - 4) * 261];
      for (int j = l8; j < 261; j += 8) p += x3[j] * w[j];
    }
    p += __shfl_xor(p, 1);
    p += __shfl_xor(p, 2);
    p += __shfl_xor(p, 4);
    if (l8 == 0) {
      if (g < 4) {
        float v = p + fc3ab[g];
        out[2304 + b * 9 + g] = (pred == 0) ? v : 0.f;
      } else if (g < 9) {
        int o = g - 4;
        float v = p + fc3bb[o];
        out[2304 + b * 9 + 4 + o] = (pred == 1) ? v : 0.f;
      }
    }
  }
}

// ---------------- Launch ----------------

extern "C" void kernel_launch(void* const* d_in, const int* in_sizes, int n_in,
                              void* d_out, int out_size, void* d_ws, size_t ws_size,
                              hipStream_t stream) {
  (void)in_sizes; (void)n_in; (void)out_size; (void)ws_size;
  const float* x   = (const float*)d_in[0];
  const int* ei    = (const int*)d_in[1];
  const int* ed    = (const int*)d_in[2];
  const int* batch = (const int*)d_in[3];
  const float* gf  = (const float*)d_in[4];

  char* ws = (char*)d_ws;
  auto carve = [&](size_t bytes) -> void* {
    void* p = ws;
    ws += (bytes + 255) & ~(size_t)255;
    return p;
  };
  int* cnt        = (int*)carve(2 * kN * sizeof(int));
  int* off        = (int*)carve(2 * kN * sizeof(int));
  int* cursor     = (int*)carve(2 * kN * sizeof(int));
  int* bsum       = (int*)carve(1024);
  int* gstart     = (int*)carve((kB + 1) * sizeof(int));
  int* csr        = (int*)carve(kE * sizeof(int));
  float* comb_raw = (float*)carve(kB * 256 * sizeof(float));
  ushort* xb      = (ushort*)carve((size_t)kNpad * 128 * 2);
  ushort* buf0    = (ushort*)carve((size_t)kNpad * 128 * 2);
  ushort* buf1    = (ushort*)carve((size_t)kNpad * 128 * 2);
  ushort* Wb      = (ushort*)carve(6 * 128 * 256 * 2);

  hipMemsetAsync(cnt, 0, 2 * kN * sizeof(int), stream);
  hipMemsetAsync(cursor, 0, 2 * kN * sizeof(int), stream);
  hipMemsetAsync(comb_raw, 0, kB * 256 * sizeof(float), stream);

  xconv_kernel<<<(kNpad * 128 / 4 + 255) / 256, 256, 0, stream>>>(x, xb);
  WPtrs wp;
  for (int L = 0; L < 6; ++L) {
    wp.Wl[L] = (const float*)d_in[6 + 3 * L];
    wp.Wr[L] = (const float*)d_in[6 + 3 * L + 2];
  }
  wprep_kernel<<<768, 256, 0, stream>>>(wp, Wb);

  count_kernel<<<(kE + 255) / 256, 256, 0, stream>>>(ei, ed, cnt);
  constexpr int M = 2 * kN;
  constexpr int NB = (M + 1023) / 1024;
  scan1_kernel<<<NB, 256, 0, stream>>>(cnt, off, bsum, M);
  scan2_kernel<<<1, 256, 0, stream>>>(bsum, NB);
  scan3_kernel<<<NB, 256, 0, stream>>>(off, bsum, M);
  fill_kernel<<<(kE + 255) / 256, 256, 0, stream>>>(ei, ed, off, cursor, csr);
  gstart_kernel<<<(kN + 255) / 256, 256, 0, stream>>>(batch, gstart);

  auto aggL = [&](const ushort* h, ushort* a, int dirbase) {
    agg_kernel<<<kN * 8 / 256 + 1, 256, 0, stream>>>(h, a, off, cnt, csr, dirbase);
  };
  auto layerL = [&](ushort* a, const ushort* h, int L) {
    layer_mfma_kernel<<<kNpad / 128, 256, 0, stream>>>(
        a, h, Wb + (size_t)L * 32768, (const float*)d_in[6 + 3 * L + 1]);
  };

  // pre chain (dir bucket base 0)
  aggL(xb, buf0, 0);     layerL(buf0, xb, 0);
  aggL(buf0, buf1, 0);   layerL(buf1, buf0, 1);
  aggL(buf1, buf0, 0);   layerL(buf0, buf1, 2);
  pool_kernel<<<kB * 16, 256, 0, stream>>>(buf0, gstart, comb_raw, 0);

  // suc chain (dir bucket base kN)
  aggL(xb, buf1, kN);    layerL(buf1, xb, 3);
  aggL(buf1, buf0, kN);  layerL(buf0, buf1, 4);
  aggL(buf0, buf1, kN);  layerL(buf1, buf0, 5);
  pool_kernel<<<kB * 16, 256, 0, stream>>>(buf1, gstart, comb_raw, 128);

  head_kernel<<<kB, 256, 0, stream>>>(
      comb_raw, gstart, gf,
      (const float*)d_in[24], (const float*)d_in[25],
      (const float*)d_in[26], (const float*)d_in[27],
      (const float*)d_in[28], (const float*)d_in[29],
      (const float*)d_in[30], (const float*)d_in[31],
      (const float*)d_in[32], (const float*)d_in[33],
      (const float*)d_in[34], (const float*)d_in[35],
      (const float*)d_in[36], (const float*)d_in[37],
      (float*)d_out);
}